// Round 1
// baseline (173.408 us; speedup 1.0000x reference)
//
#include <hip/hip_runtime.h>
#include <hip/hip_bf16.h>
#include <stdint.h>

// out[4096,4096] = x[4096,2048] @ matrix[0,4096,2048]^T   (fp32 in/out)
// R4: cast pass unchanged. GEMM restructured to the 256x256 8-wave 4-phase
// counted-vmcnt schedule (T3+T4+T5): BK=64, 2x64KB double-buffered LDS
// (128 KiB), raw s_barrier + manual waitcnt (no vmcnt(0) drain in steady
// state), setprio(1) around each 16-MFMA quadrant cluster, XCD-chunked
// block swizzle. R3's verified XOR chunk-swizzle (0 bank conflicts) and
// fragment/epilogue layout retained. 1 block/CU (512 thr, 8 waves).

#define GAS __attribute__((address_space(1)))
#define LAS __attribute__((address_space(3)))

typedef __bf16 bf16x8 __attribute__((ext_vector_type(8)));
typedef float f32x4 __attribute__((ext_vector_type(4)));

static __device__ __forceinline__ unsigned short f2bf(float f) {
  union { float f; uint32_t u; } a; a.f = f;
  uint32_t u = a.u;
  u += 0x7FFFu + ((u >> 16) & 1u);   // round-to-nearest-even
  return (unsigned short)(u >> 16);
}

__global__ void cvt_f32_to_bf16(const float4* __restrict__ x,
                                const float4* __restrict__ m,
                                ushort4* __restrict__ xo,
                                ushort4* __restrict__ mo) {
  const int i = blockIdx.x * blockDim.x + threadIdx.x;
  const float4* __restrict__ src = blockIdx.y ? m : x;
  ushort4* __restrict__ dst      = blockIdx.y ? mo : xo;
  float4 v = src[i];
  ushort4 o;
  o.x = f2bf(v.x); o.y = f2bf(v.y); o.z = f2bf(v.z); o.w = f2bf(v.w);
  dst[i] = o;
}

#define MFMA16(a, b, c) __builtin_amdgcn_mfma_f32_16x16x32_bf16((a), (b), (c), 0, 0, 0)

// C[M,N] = A[M,K]*B[N,K]^T, M=N=4096, K=2048. 512 threads = 8 waves.
// Block tile 256x256; wave (wm=wave>>2, wn=wave&3) owns rows wm*128..+128,
// cols wn*64..+64 as acc[8][4] of 16x16 frags. BK=64, NT=32 K-tiles.
// LDS: lds[buf][A/B][256*64], XOR swizzle: global chunk c of row r stored
// at physical chunk c^(r&7) (chunks = 8 elems = 16B).
// Schedule per K-tile t (buf p=t&1), 4 phases, each {ds_read | barrier |
// setprio+16 MFMA | barrier}:
//   ph1: read aF(i0-3,2ks)+bF01(2ks) [12]       -> MFMA Q0 = (i0-3)x(j0-1)
//   ph2: read bF23 [4]                          -> MFMA Q1 = (i0-3)x(j2-3)
//   ph3: read aF(i4-7) [8]; lgkmcnt(0)          -> MFMA Q2 = (i4-7)x(j2-3)
//        (post-ph3 barrier == all waves done reading buf p)
//   ph4: STAGE(t+2 -> buf p); vmcnt(8)          -> MFMA Q3 = (i4-7)x(j0-1)
//        (vmcnt(8) leaves tile t+2's 8 loads in flight; waits tile t+1)
// bF01 is held in regs ph1->ph4 (no ph4 ds_read: buf p is being overwritten
// by in-flight stage loads there). Tail: t=NT-2 uses vmcnt(0).
__global__ __launch_bounds__(512, 2)
void gemm_bt_bf16(const unsigned short* __restrict__ A,
                  const unsigned short* __restrict__ B,
                  float* __restrict__ C) {
  constexpr int K  = 2048;
  constexpr int N  = 4096;
  constexpr int NT = K / 64;   // 32 K-tiles

  __shared__ __align__(16) unsigned short lds[2][2][256 * 64];   // 128 KiB

  const int tid  = threadIdx.x;
  const int wave = tid >> 6;
  const int lane = tid & 63;
  const int wm   = wave >> 2;   // 0..1
  const int wn   = wave & 3;    // 0..3

  // XCD-chunked swizzle: 256 blocks on 16x16 tiles; XCD x gets tile-rows
  // [2x, 2x+2) full width (32 consecutive swizzled ids per XCD).
  const int bid = blockIdx.x;
  const int tm  = (bid & 7) * 2 + ((bid >> 3) >> 4);
  const int tn  = (bid >> 3) & 15;
  const int bM  = tm * 256;
  const int bN  = tn * 256;

  const int quad = lane >> 4;   // 0..3
  const int l15  = lane & 15;
  const int mx   = l15 & 7;     // = row&7 for all fragment rows

  // Staging: wave w covers rows [w*32, w*32+32) of A and of B, 4 insts each
  // (8 rows/inst). lane -> row lr=lane>>3, pre-swizzled source chunk lc.
  const int lr = lane >> 3;
  const int lc = (lane & 7) ^ lr;
  const size_t aBase = (size_t)(bM + wave * 32 + lr) * K + lc * 8;
  const size_t bBase = (size_t)(bN + wave * 32 + lr) * K + lc * 8;
  const int ldsW = wave * 32 * 64;   // elems

  // Per-lane fragment offsets (elems). Physical chunk = (ks*4+quad)^mx.
  const int aOff = (wm * 128 + l15) * 64;
  const int bOff = (wn * 64  + l15) * 64;
  const int ko0  = ((0 * 4 + quad) ^ mx) << 3;
  const int ko1  = ((1 * 4 + quad) ^ mx) << 3;

  f32x4 acc[8][4] = {};

#define STAGE(tau, pp) do {                                                              \
    const size_t kk_ = (size_t)(tau) * 64;                                               \
    _Pragma("unroll")                                                                    \
    for (int u = 0; u < 4; ++u)                                                          \
      __builtin_amdgcn_global_load_lds((const GAS void*)(A + aBase + kk_ + (size_t)u * 8 * K), \
                                       (LAS void*)(&lds[pp][0][ldsW + u * 512]), 16, 0, 0);    \
    _Pragma("unroll")                                                                    \
    for (int u = 0; u < 4; ++u)                                                          \
      __builtin_amdgcn_global_load_lds((const GAS void*)(B + bBase + kk_ + (size_t)u * 8 * K), \
                                       (LAS void*)(&lds[pp][1][ldsW + u * 512]), 16, 0, 0);    \
  } while (0)

  // Prologue: stage tiles 0 and 1; wait tile 0 only (tile 1 stays in flight).
  STAGE(0, 0);
  STAGE(1, 1);
  asm volatile("s_waitcnt vmcnt(8)" ::: "memory");
  __builtin_amdgcn_sched_barrier(0);
  __builtin_amdgcn_s_barrier();

  bf16x8 aF[4][2], bF01[2][2], bF23[2][2];

  for (int t = 0; t < NT; ++t) {
    const int p = t & 1;
    const unsigned short* As = lds[p][0];
    const unsigned short* Bs = lds[p][1];

    // ---- phase 1: Q0 = (i0-3) x (j0-1) ----
#pragma unroll
    for (int i = 0; i < 4; ++i) {
      aF[i][0] = *(const bf16x8*)(As + aOff + i * 1024 + ko0);
      aF[i][1] = *(const bf16x8*)(As + aOff + i * 1024 + ko1);
    }
#pragma unroll
    for (int j = 0; j < 2; ++j) {
      bF01[j][0] = *(const bf16x8*)(Bs + bOff + j * 1024 + ko0);
      bF01[j][1] = *(const bf16x8*)(Bs + bOff + j * 1024 + ko1);
    }
    __builtin_amdgcn_s_barrier();
    __builtin_amdgcn_s_setprio(1);
#pragma unroll
    for (int i = 0; i < 4; ++i)
#pragma unroll
      for (int j = 0; j < 2; ++j) {
        acc[i][j] = MFMA16(aF[i][0], bF01[j][0], acc[i][j]);
        acc[i][j] = MFMA16(aF[i][1], bF01[j][1], acc[i][j]);
      }
    __builtin_amdgcn_s_setprio(0);
    __builtin_amdgcn_s_barrier();

    // ---- phase 2: Q1 = (i0-3) x (j2-3) ----
#pragma unroll
    for (int j = 0; j < 2; ++j) {
      bF23[j][0] = *(const bf16x8*)(Bs + bOff + (2 + j) * 1024 + ko0);
      bF23[j][1] = *(const bf16x8*)(Bs + bOff + (2 + j) * 1024 + ko1);
    }
    __builtin_amdgcn_s_barrier();
    __builtin_amdgcn_s_setprio(1);
#pragma unroll
    for (int i = 0; i < 4; ++i)
#pragma unroll
      for (int j = 0; j < 2; ++j) {
        acc[i][2 + j] = MFMA16(aF[i][0], bF23[j][0], acc[i][2 + j]);
        acc[i][2 + j] = MFMA16(aF[i][1], bF23[j][1], acc[i][2 + j]);
      }
    __builtin_amdgcn_s_setprio(0);
    __builtin_amdgcn_s_barrier();

    // ---- phase 3: Q2 = (i4-7) x (j2-3) ----
#pragma unroll
    for (int i = 0; i < 4; ++i) {
      aF[i][0] = *(const bf16x8*)(As + aOff + (4 + i) * 1024 + ko0);
      aF[i][1] = *(const bf16x8*)(As + aOff + (4 + i) * 1024 + ko1);
    }
    asm volatile("s_waitcnt lgkmcnt(0)" ::: "memory");   // all my buf-p reads done
    __builtin_amdgcn_sched_barrier(0);
    __builtin_amdgcn_s_barrier();                        // -> buf p free for staging
    __builtin_amdgcn_s_setprio(1);
#pragma unroll
    for (int i = 0; i < 4; ++i)
#pragma unroll
      for (int j = 0; j < 2; ++j) {
        acc[4 + i][2 + j] = MFMA16(aF[i][0], bF23[j][0], acc[4 + i][2 + j]);
        acc[4 + i][2 + j] = MFMA16(aF[i][1], bF23[j][1], acc[4 + i][2 + j]);
      }
    __builtin_amdgcn_s_setprio(0);
    __builtin_amdgcn_s_barrier();

    // ---- phase 4: Q3 = (i4-7) x (j0-1); stage tile t+2 into buf p ----
    if (t + 2 < NT) {
      STAGE(t + 2, p);
      asm volatile("s_waitcnt vmcnt(8)" ::: "memory");   // tile t+1 landed; t+2 in flight
    } else if (t + 1 < NT) {
      asm volatile("s_waitcnt vmcnt(0)" ::: "memory");   // tail: drain tile t+1
    }
    __builtin_amdgcn_sched_barrier(0);
    __builtin_amdgcn_s_barrier();
    __builtin_amdgcn_s_setprio(1);
#pragma unroll
    for (int i = 0; i < 4; ++i)
#pragma unroll
      for (int j = 0; j < 2; ++j) {
        acc[4 + i][j] = MFMA16(aF[i][0], bF01[j][0], acc[4 + i][j]);
        acc[4 + i][j] = MFMA16(aF[i][1], bF01[j][1], acc[4 + i][j]);
      }
    __builtin_amdgcn_s_setprio(0);
    __builtin_amdgcn_s_barrier();
  }
#undef STAGE

  // Epilogue: C/D layout col=lane&15, row=quad*4+reg (m89-verified).
#pragma unroll
  for (int i = 0; i < 8; ++i) {
    const int row0 = bM + wm * 128 + i * 16 + quad * 4;
#pragma unroll
    for (int j = 0; j < 4; ++j) {
      const int col = bN + wn * 64 + j * 16 + l15;
#pragma unroll
      for (int tt = 0; tt < 4; ++tt)
        C[(size_t)(row0 + tt) * N + col] = acc[i][j][tt];
    }
  }
}

extern "C" void kernel_launch(void* const* d_in, const int* in_sizes, int n_in,
                              void* d_out, int out_size, void* d_ws, size_t ws_size,
                              hipStream_t stream) {
  const float* x   = (const float*)d_in[0];   // [4096, 2048]
  const float* mat = (const float*)d_in[1];   // [1, 4096, 2048]
  float* out = (float*)d_out;                 // [4096, 4096]

  constexpr size_t ELEMS = 4096ull * 2048ull;
  unsigned short* xb = (unsigned short*)d_ws;
  unsigned short* mb = xb + ELEMS;

  dim3 cgrid((unsigned)(ELEMS / 4 / 256), 2);
  cvt_f32_to_bf16<<<cgrid, 256, 0, stream>>>((const float4*)x, (const float4*)mat,
                                             (ushort4*)xb, (ushort4*)mb);

  // 256 blocks = 16x16 tiles of 256x256, 1 block/CU, XCD-swizzled in-kernel.
  gemm_bt_bf16<<<dim3(256), 512, 0, stream>>>(xb, mb, out);
}

// Round 2
// 165.180 us; speedup vs baseline: 1.0498x; 1.0498x over previous
//
#include <hip/hip_runtime.h>
#include <hip/hip_bf16.h>
#include <stdint.h>

// out[4096,4096] = x[4096,2048] @ matrix[0,4096,2048]^T   (fp32 in/out)
// R5: cast pass unchanged. GEMM: 256x256 tile, 8 waves, BK=64, double-buffered
// 128 KiB LDS, counted vmcnt -- but only TWO barriers per K-tile (R4's 8
// lockstep barriers serialized LDS bursts against MFMA bursts at 2 waves/SIMD
// and regressed to 80us). All 24 ds_reads issue up front; MFMA Q0+Q1 overlap
// them (compiler's fine lgkmcnt); mid lgkmcnt(0)+barrier frees buf p; STAGE
// t+2 issues under MFMA Q2+Q3; end vmcnt(8)+barrier admits tile t+1.
// Steady state never drains vmcnt to 0. R3's verified XOR chunk swizzle
// (0 bank conflicts) and m89-verified C/D layout retained.

#define GAS __attribute__((address_space(1)))
#define LAS __attribute__((address_space(3)))

typedef __bf16 bf16x8 __attribute__((ext_vector_type(8)));
typedef float f32x4 __attribute__((ext_vector_type(4)));

static __device__ __forceinline__ unsigned short f2bf(float f) {
  union { float f; uint32_t u; } a; a.f = f;
  uint32_t u = a.u;
  u += 0x7FFFu + ((u >> 16) & 1u);   // round-to-nearest-even
  return (unsigned short)(u >> 16);
}

__global__ void cvt_f32_to_bf16(const float4* __restrict__ x,
                                const float4* __restrict__ m,
                                ushort4* __restrict__ xo,
                                ushort4* __restrict__ mo) {
  const int i = blockIdx.x * blockDim.x + threadIdx.x;
  const float4* __restrict__ src = blockIdx.y ? m : x;
  ushort4* __restrict__ dst      = blockIdx.y ? mo : xo;
  float4 v = src[i];
  ushort4 o;
  o.x = f2bf(v.x); o.y = f2bf(v.y); o.z = f2bf(v.z); o.w = f2bf(v.w);
  dst[i] = o;
}

#define MFMA16(a, b, c) __builtin_amdgcn_mfma_f32_16x16x32_bf16((a), (b), (c), 0, 0, 0)

// C[M,N] = A[M,K]*B[N,K]^T, M=N=4096, K=2048. 512 threads = 8 waves.
// Block tile 256x256; wave (wm=wave>>2, wn=wave&3) owns rows wm*128..+128,
// cols wn*64..+64 as acc[8][4] of 16x16 frags. BK=64, NT=32 K-tiles.
// LDS: lds[buf][A/B][256*64]; global chunk c (8 elems=16B) of row r stored
// at physical chunk c^(r&7).
// Per K-tile t (buf p=t&1):
//   ds_read all 24 frags from buf p;  MFMA rows 0-3 (32 mfma, overlaps reads)
//   lgkmcnt(0); barrier              -> every wave's reads of buf p done
//   STAGE(t+2 -> buf p)              -> overwrite is now safe
//   MFMA rows 4-7 (32 mfma, hides stage issue)
//   vmcnt(8); barrier                -> tile t+1 landed (t+2's 8 stay in flight)
__global__ __launch_bounds__(512, 2)
void gemm_bt_bf16(const unsigned short* __restrict__ A,
                  const unsigned short* __restrict__ B,
                  float* __restrict__ C) {
  constexpr int K  = 2048;
  constexpr int N  = 4096;
  constexpr int NT = K / 64;   // 32 K-tiles

  __shared__ __align__(16) unsigned short lds[2][2][256 * 64];   // 128 KiB

  const int tid  = threadIdx.x;
  const int wave = tid >> 6;
  const int lane = tid & 63;
  const int wm   = wave >> 2;   // 0..1
  const int wn   = wave & 3;    // 0..3

  // XCD-chunked swizzle (bijective over 256 blocks): XCD x gets tile-rows
  // [2x, 2x+2) -> 32 consecutive swizzled ids per XCD share 2 A-panels.
  const int bid = blockIdx.x;
  const int tm  = (bid & 7) * 2 + ((bid >> 3) >> 4);
  const int tn  = (bid >> 3) & 15;
  const int bM  = tm * 256;
  const int bN  = tn * 256;

  const int quad = lane >> 4;   // 0..3
  const int l15  = lane & 15;
  const int mx   = l15 & 7;     // = row&7 for all fragment rows

  // Staging: wave w covers rows [w*32, w*32+32) of A and of B, 4 insts each
  // (8 rows/inst). lane -> row lr=lane>>3, pre-swizzled source chunk lc.
  const int lr = lane >> 3;
  const int lc = (lane & 7) ^ lr;
  const size_t aBase = (size_t)(bM + wave * 32 + lr) * K + lc * 8;
  const size_t bBase = (size_t)(bN + wave * 32 + lr) * K + lc * 8;
  const int ldsW = wave * 32 * 64;   // elems

  // Per-lane fragment offsets (elems). Physical chunk = (ks*4+quad)^mx.
  const int aOff = (wm * 128 + l15) * 64;
  const int bOff = (wn * 64  + l15) * 64;
  const int ko0  = ((0 * 4 + quad) ^ mx) << 3;
  const int ko1  = ((1 * 4 + quad) ^ mx) << 3;

  f32x4 acc[8][4] = {};

#define STAGE(tau, pp) do {                                                              \
    const size_t kk_ = (size_t)(tau) * 64;                                               \
    _Pragma("unroll")                                                                    \
    for (int u = 0; u < 4; ++u)                                                          \
      __builtin_amdgcn_global_load_lds((const GAS void*)(A + aBase + kk_ + (size_t)u * 8 * K), \
                                       (LAS void*)(&lds[pp][0][ldsW + u * 512]), 16, 0, 0);    \
    _Pragma("unroll")                                                                    \
    for (int u = 0; u < 4; ++u)                                                          \
      __builtin_amdgcn_global_load_lds((const GAS void*)(B + bBase + kk_ + (size_t)u * 8 * K), \
                                       (LAS void*)(&lds[pp][1][ldsW + u * 512]), 16, 0, 0);    \
  } while (0)

  // Prologue: stage tiles 0 and 1; wait tile 0 only (tile 1 stays in flight).
  STAGE(0, 0);
  STAGE(1, 1);
  asm volatile("s_waitcnt vmcnt(8)" ::: "memory");
  __builtin_amdgcn_sched_barrier(0);
  __builtin_amdgcn_s_barrier();
  __builtin_amdgcn_sched_barrier(0);

  for (int t = 0; t < NT; ++t) {
    const int p = t & 1;
    const unsigned short* As = lds[p][0];
    const unsigned short* Bs = lds[p][1];

    // ---- all fragment reads for this K-tile (24 x ds_read_b128) ----
    bf16x8 aF[8][2], bF[4][2];
#pragma unroll
    for (int i = 0; i < 8; ++i) {
      aF[i][0] = *(const bf16x8*)(As + aOff + i * 1024 + ko0);
      aF[i][1] = *(const bf16x8*)(As + aOff + i * 1024 + ko1);
    }
#pragma unroll
    for (int j = 0; j < 4; ++j) {
      bF[j][0] = *(const bf16x8*)(Bs + bOff + j * 1024 + ko0);
      bF[j][1] = *(const bf16x8*)(Bs + bOff + j * 1024 + ko1);
    }

    // ---- MFMA rows 0-3 (32) — scheduler interleaves with the reads ----
    __builtin_amdgcn_s_setprio(1);
#pragma unroll
    for (int i = 0; i < 4; ++i)
#pragma unroll
      for (int j = 0; j < 4; ++j) {
        acc[i][j] = MFMA16(aF[i][0], bF[j][0], acc[i][j]);
        acc[i][j] = MFMA16(aF[i][1], bF[j][1], acc[i][j]);
      }
    __builtin_amdgcn_s_setprio(0);

    // ---- free buf p, then stage tile t+2 into it ----
    if (t + 2 < NT) {
      asm volatile("s_waitcnt lgkmcnt(0)" ::: "memory");   // my 24 reads done
      __builtin_amdgcn_sched_barrier(0);
      __builtin_amdgcn_s_barrier();                        // everyone's done
      __builtin_amdgcn_sched_barrier(0);
      STAGE(t + 2, p);
    }

    // ---- MFMA rows 4-7 (32) — hides the stage issue ----
    __builtin_amdgcn_s_setprio(1);
#pragma unroll
    for (int i = 4; i < 8; ++i)
#pragma unroll
      for (int j = 0; j < 4; ++j) {
        acc[i][j] = MFMA16(aF[i][0], bF[j][0], acc[i][j]);
        acc[i][j] = MFMA16(aF[i][1], bF[j][1], acc[i][j]);
      }
    __builtin_amdgcn_s_setprio(0);

    // ---- admit tile t+1 (counted wait; never 0 until the tail) ----
    if (t + 1 < NT) {
      if (t + 2 < NT) asm volatile("s_waitcnt vmcnt(8)" ::: "memory");
      else            asm volatile("s_waitcnt vmcnt(0)" ::: "memory");
      __builtin_amdgcn_sched_barrier(0);
      __builtin_amdgcn_s_barrier();
      __builtin_amdgcn_sched_barrier(0);
    }
  }
#undef STAGE

  // Epilogue: C/D layout col=lane&15, row=quad*4+reg (m89-verified).
#pragma unroll
  for (int i = 0; i < 8; ++i) {
    const int row0 = bM + wm * 128 + i * 16 + quad * 4;
#pragma unroll
    for (int j = 0; j < 4; ++j) {
      const int col = bN + wn * 64 + j * 16 + l15;
#pragma unroll
      for (int tt = 0; tt < 4; ++tt)
        C[(size_t)(row0 + tt) * N + col] = acc[i][j][tt];
    }
  }
}

extern "C" void kernel_launch(void* const* d_in, const int* in_sizes, int n_in,
                              void* d_out, int out_size, void* d_ws, size_t ws_size,
                              hipStream_t stream) {
  const float* x   = (const float*)d_in[0];   // [4096, 2048]
  const float* mat = (const float*)d_in[1];   // [1, 4096, 2048]
  float* out = (float*)d_out;                 // [4096, 4096]

  constexpr size_t ELEMS = 4096ull * 2048ull;
  unsigned short* xb = (unsigned short*)d_ws;
  unsigned short* mb = xb + ELEMS;

  dim3 cgrid((unsigned)(ELEMS / 4 / 256), 2);
  cvt_f32_to_bf16<<<cgrid, 256, 0, stream>>>((const float4*)x, (const float4*)mat,
                                             (ushort4*)xb, (ushort4*)mb);

  // 256 blocks = 16x16 tiles of 256x256, 1 block/CU, XCD-swizzled in-kernel.
  gemm_bt_bf16<<<dim3(256), 512, 0, stream>>>(xb, mb, out);
}